// Round 9
// baseline (1456.193 us; speedup 1.0000x reference)
//
#include <hip/hip_runtime.h>
#include <hip/hip_bf16.h>
#include <math.h>

#define H 512
#define V 128
#define NLEAF 16384

typedef __attribute__((ext_vector_type(4))) float f32x4;
typedef __attribute__((ext_vector_type(8))) short s16x8;
typedef __attribute__((ext_vector_type(4))) unsigned short u16x4;
typedef unsigned short ushort_t;

// ---- static device scratch ----
__device__ ushort_t g_hb0[NLEAF * H];        // h bf16 (levels 14,12,...,0)
__device__ ushort_t g_hb1[(NLEAF / 2) * H];  // h bf16 (levels 13,11,...,1)
__device__ float    g_c0[NLEAF * H];         // c f32
__device__ float    g_c1[(NLEAF / 2) * H];
__device__ ushort_t g_UiouT[3 * H * 2 * H];  // [1536 cols][1024 k] bf16 (binary)
__device__ ushort_t g_UfT[H * 2 * H];        // [512 cols][1024 k] bf16 (f0|f1 halves)
__device__ ushort_t g_UiouTt[3 * H * 3 * H]; // [1536 cols][1536 k] bf16 (root)
__device__ ushort_t g_UfTt[H * 3 * H];       // [512 cols][1536 k] bf16 (f0|f1|f2)
__device__ float    g_rpart[3 * 3072];       // root k-chunk partials
__device__ float    g_hf[H];
__device__ float    g_gates[4 * H];

__device__ __forceinline__ float sigm(float x) { return 1.0f / (1.0f + __expf(-x)); }
__device__ __forceinline__ float ftanh(float x) {
  return 1.0f - 2.0f / (__expf(2.0f * x) + 1.0f);
}
__device__ __forceinline__ ushort_t f2bf(float x) {
  __hip_bfloat16 b = __float2bfloat16(x);
  return *reinterpret_cast<ushort_t*>(&b);
}
__device__ __forceinline__ float bf2f(ushort_t u) {
  union { unsigned int i; float f; } v; v.i = ((unsigned int)u) << 16; return v.f;
}
__device__ __forceinline__ void gload_lds16(const void* g, void* l) {
  __builtin_amdgcn_global_load_lds(
      (const __attribute__((address_space(1))) unsigned int*)g,
      (__attribute__((address_space(3))) unsigned int*)l, 16, 0, 0);
}

// ---------------- prep: 4 weight transposes (z<4) + leaf level (z==4) ------
__global__ __launch_bounds__(256) void k_prep(
    const float* __restrict__ s0, const float* __restrict__ s1,
    const float* __restrict__ s2, const float* __restrict__ s3,
    ushort_t* __restrict__ d0, ushort_t* __restrict__ d1,
    ushort_t* __restrict__ d2, ushort_t* __restrict__ d3,
    const int* __restrict__ tokens,
    const float* __restrict__ Wiou, const float* __restrict__ biou) {
  if (blockIdx.z == 4) {                     // ---- leaf (lvl 14) ----
    const int total = NLEAF * 128;           // quads
    const int bid = blockIdx.y * 48 + blockIdx.x;
    for (int q = bid * 256 + threadIdx.x; q < total; q += 2304 * 256) {
      int i = q >> 7, jv = q & 127;
      int tok = tokens[(NLEAF - 1) + i];
      const f32x4* Wr = (const f32x4*)(Wiou + (size_t)tok * 1536);
      const f32x4* bv = (const f32x4*)biou;
      f32x4 wi = Wr[jv] + bv[jv];
      f32x4 wo = Wr[128 + jv] + bv[128 + jv];
      f32x4 wu = Wr[256 + jv] + bv[256 + jv];
      u16x4 hv; f32x4 cv;
      #pragma unroll
      for (int r = 0; r < 4; ++r) {
        float c = sigm(wi[r]) * ftanh(wu[r]);
        float h = sigm(wo[r]) * ftanh(c);
        cv[r] = c;
        hv[r] = f2bf(h);
      }
      *reinterpret_cast<u16x4*>(&g_hb0[(size_t)q * 4]) = hv;
      *reinterpret_cast<f32x4*>(&g_c0[(size_t)q * 4]) = cv;
    }
    return;
  }
  // ---- transpose+bf16: dst[c][r] = bf16(src[r][c]) ----
  const float* src; ushort_t* dst; int R, Cc;
  switch (blockIdx.z) {
    case 0: src = s0; dst = d0; R = 1024; Cc = 1536; break;
    case 1: src = s1; dst = d1; R = 1024; Cc = 512; break;
    case 2: src = s2; dst = d2; R = 1536; Cc = 1536; break;
    default: src = s3; dst = d3; R = 1536; Cc = 512; break;
  }
  int bc = blockIdx.x * 32, br = blockIdx.y * 32;
  if (bc >= Cc || br >= R) return;
  __shared__ float t[32][33];
  int tx = threadIdx.x & 31, ty = threadIdx.x >> 5;
  for (int rr = ty; rr < 32; rr += 8)
    t[rr][tx] = src[(size_t)(br + rr) * Cc + bc + tx];
  __syncthreads();
  for (int rr = ty; rr < 32; rr += 8)
    dst[(size_t)(bc + rr) * R + br + tx] = f2bf(t[tx][rr]);
}

// ---------------- big levels (n >= 256): MFMA bf16 fused cell --------------
// 256 thr = 4 waves (2 row x 2 col). Tile: 128 nodes x 64 j-cols x 5 gates.
// Depth-2 counted-vmcnt pipeline; 48KB LDS -> 3 blocks/CU (12 waves/CU).
// 1D grid with XCD-chunked swizzle: 8 j-blocks sharing an A-tile -> same XCD.
__global__ __launch_bounds__(256, 3) void k_mfma_lvl(int lvl,
    const int* __restrict__ tokens,
    const float* __restrict__ Wiou, const float* __restrict__ biou,
    const float* __restrict__ Wf, const float* __restrict__ bf) {
  const int n = 1 << lvl;
  const int node0 = n - 1;
  const int outp = lvl & 1;
  const ushort_t* __restrict__ hprev = outp ? g_hb0 : g_hb1;
  const float* __restrict__ cprev = outp ? g_c0 : g_c1;
  ushort_t* __restrict__ hout = outp ? g_hb1 : g_hb0;
  float* __restrict__ cout = outp ? g_c1 : g_c0;

  // XCD-chunked bijective swizzle (grid size always % 8 == 0 here)
  const int orig = blockIdx.x;
  const int qch = gridDim.x >> 3;
  const int wg = (orig & 7) * qch + (orig >> 3);
  const int i0 = (wg >> 3) * 128;
  const int j0 = (wg & 7) * 64;

  const int tid = threadIdx.x;
  const int lane = tid & 63;
  const int w = tid >> 6;        // 0..3
  const int wry = w >> 1;        // row half
  const int cx = w & 1;          // col half

  __shared__ f32x4 smemv[3072];  // 48KB: A 2x8KB @0, B 2x16KB @16384
  char* smem = (char*)smemv;

  const char* gp[6];
  unsigned lb[6], lstride[6];
  {
    int kb = (lane >> 4) * 16;
    #pragma unroll
    for (int q = 0; q < 6; ++q) {
      int c = w * 6 + q;
      if (c < 8) {               // A chunk, row-tile c
        int row = i0 + c * 16 + (lane & 15);
        gp[q] = (const char*)hprev + (size_t)row * 2048 + kb;
        lb[q] = c * 1024u;
        lstride[q] = 8192u;
      } else {                   // B chunk, col-tile ct
        int ct = c - 8;
        int col = ct * 16 + (lane & 15);
        int g = col >> 6, jj = j0 + (col & 63);
        const ushort_t* Ub = (g < 3) ? (g_UiouT + (size_t)(g * 512 + jj) * 1024)
                                     : (g_UfT + (size_t)jj * 1024);
        gp[q] = (const char*)Ub + kb;
        lb[q] = 16384u + ct * 1024u;
        lstride[q] = 16384u;
      }
    }
  }

#define STAGE(BUF)                                                   \
  {                                                                  \
    _Pragma("unroll")                                                \
    for (int q = 0; q < 6; ++q) {                                    \
      gload_lds16(gp[q], smem + lb[q] + (unsigned)(BUF) * lstride[q]); \
      gp[q] += 64;                                                   \
    }                                                                \
  }
#define WAITV(N) asm volatile("s_waitcnt vmcnt(" #N ")" ::: "memory")
#define BAR_IN()  { __builtin_amdgcn_s_barrier(); __builtin_amdgcn_sched_barrier(0); }

  f32x4 acc[4][10];
  #pragma unroll
  for (int a = 0; a < 4; ++a)
    #pragma unroll
    for (int b = 0; b < 10; ++b) acc[a][b] = (f32x4){0.f, 0.f, 0.f, 0.f};

#define COMPUTE(FA)                                                          \
  {                                                                          \
    const char* ab = smem + buf * 8192 + wry * 4096 + lane * 16;             \
    s16x8 a0 = *(const s16x8*)(ab);                                          \
    s16x8 a1 = *(const s16x8*)(ab + 1024);                                   \
    s16x8 a2 = *(const s16x8*)(ab + 2048);                                   \
    s16x8 a3 = *(const s16x8*)(ab + 3072);                                   \
    const char* bb = smem + 16384 + buf * 16384 + cx * 2048 + lane * 16;     \
    s16x8 b0 = *(const s16x8*)(bb);                                          \
    s16x8 b1 = *(const s16x8*)(bb + 1024);                                   \
    s16x8 b2 = *(const s16x8*)(bb + 4096);                                   \
    s16x8 b3 = *(const s16x8*)(bb + 5120);                                   \
    s16x8 b4 = *(const s16x8*)(bb + 8192);                                   \
    s16x8 b5 = *(const s16x8*)(bb + 9216);                                   \
    s16x8 b6 = *(const s16x8*)(bb + 12288);                                  \
    s16x8 b7 = *(const s16x8*)(bb + 13312);                                  \
    s16x8 aa[4] = {a0, a1, a2, a3};                                          \
    __builtin_amdgcn_s_setprio(1);                                           \
    _Pragma("unroll")                                                        \
    for (int rtl = 0; rtl < 4; ++rtl) {                                      \
      acc[rtl][0] = __builtin_amdgcn_mfma_f32_16x16x32_bf16(aa[rtl], b0, acc[rtl][0], 0, 0, 0); \
      acc[rtl][1] = __builtin_amdgcn_mfma_f32_16x16x32_bf16(aa[rtl], b1, acc[rtl][1], 0, 0, 0); \
      acc[rtl][2] = __builtin_amdgcn_mfma_f32_16x16x32_bf16(aa[rtl], b2, acc[rtl][2], 0, 0, 0); \
      acc[rtl][3] = __builtin_amdgcn_mfma_f32_16x16x32_bf16(aa[rtl], b3, acc[rtl][3], 0, 0, 0); \
      acc[rtl][4] = __builtin_amdgcn_mfma_f32_16x16x32_bf16(aa[rtl], b4, acc[rtl][4], 0, 0, 0); \
      acc[rtl][5] = __builtin_amdgcn_mfma_f32_16x16x32_bf16(aa[rtl], b5, acc[rtl][5], 0, 0, 0); \
      acc[rtl][FA] = __builtin_amdgcn_mfma_f32_16x16x32_bf16(aa[rtl], b6, acc[rtl][FA], 0, 0, 0); \
      acc[rtl][FA + 1] = __builtin_amdgcn_mfma_f32_16x16x32_bf16(aa[rtl], b7, acc[rtl][FA + 1], 0, 0, 0); \
    }                                                                        \
    __builtin_amdgcn_s_setprio(0);                                           \
  }

  // prologue: stage kt=0,1 (12 loads in flight)
  STAGE(0); STAGE(1);
  int buf = 0;
  // main: WAITV(6) -> only this kt's 6 loads must land; kt+1's stay in
  // flight across the barrier. Post-compute barrier protects the overwrite.
  for (int kt = 0; kt < 16; ++kt) {
    WAITV(6);
    BAR_IN();
    COMPUTE(6);
    BAR_IN();
    STAGE(buf);
    buf ^= 1;
  }
  for (int kt = 16; kt < 30; ++kt) {
    WAITV(6);
    BAR_IN();
    COMPUTE(8);
    BAR_IN();
    STAGE(buf);
    buf ^= 1;
  }
  // tail: kt=30,31 — no more staging
  WAITV(6); BAR_IN(); COMPUTE(8); buf ^= 1;
  WAITV(0); BAR_IN(); COMPUTE(8);
#undef COMPUTE
#undef STAGE
#undef WAITV
#undef BAR_IN

  const int node_c = lane >> 4;
  const int jl = lane & 15;
  #pragma unroll
  for (int t = 0; t < 2; ++t) {
    const int j = j0 + cx * 32 + t * 16 + jl;
    const float bi = biou[j], bo = biou[512 + j], bu = biou[1024 + j], bfv = bf[j];
    #pragma unroll
    for (int rtl = 0; rtl < 4; ++rtl) {
      f32x4 vi = acc[rtl][0 + t], vo = acc[rtl][2 + t], vu = acc[rtl][4 + t],
            v0 = acc[rtl][6 + t], v1 = acc[rtl][8 + t];
      const int ib = i0 + wry * 64 + rtl * 16 + node_c * 4;
      #pragma unroll
      for (int r = 0; r < 4; ++r) {
        int i = ib + r;
        int tok = tokens[node0 + i];
        const float* Wr = Wiou + (size_t)tok * 1536;
        float fpre = Wf[(size_t)tok * 512 + j] + bfv;
        float ig = vi[r] + Wr[j] + bi;
        float og = vo[r] + Wr[512 + j] + bo;
        float ug = vu[r] + Wr[1024 + j] + bu;
        float cc = sigm(ig) * ftanh(ug)
                 + sigm(fpre + v0[r]) * cprev[(size_t)(2 * i) * 512 + j]
                 + sigm(fpre + v1[r]) * cprev[(size_t)(2 * i + 1) * 512 + j];
        float hh = sigm(og) * ftanh(cc);
        hout[(size_t)i * 512 + j] = f2bf(hh);
        cout[(size_t)i * 512 + j] = cc;
      }
    }
  }
}

// ------------- small levels (n <= 128): single fused GEMV kernel -----------
__global__ __launch_bounds__(256) void k_small(int lvl,
    const int* __restrict__ tokens,
    const float* __restrict__ Wiou, const float* __restrict__ biou,
    const float* __restrict__ Wf, const float* __restrict__ bf) {
  const int n = 1 << lvl;
  const int node0 = n - 1;
  const int outp = lvl & 1;
  const ushort_t* __restrict__ hprev = outp ? g_hb0 : g_hb1;
  const float* __restrict__ cprev = outp ? g_c0 : g_c1;
  ushort_t* __restrict__ hout = outp ? g_hb1 : g_hb0;
  float* __restrict__ cout = outp ? g_c1 : g_c0;

  const int i = blockIdx.y;
  const int j0 = blockIdx.x * 64;
  const int tid = threadIdx.x;
  const int g = tid >> 6;
  const int jc = tid & 63;
  const int jj = j0 + jc;

  __shared__ float hl[1024];
  __shared__ float exch[5][64];
  for (int t = tid; t < 1024; t += 256) hl[t] = bf2f(hprev[(size_t)i * 1024 + t]);
  __syncthreads();

  const ushort_t* col = (g < 3) ? (g_UiouT + (size_t)(g * 512 + jj) * 1024)
                                : (g_UfT + (size_t)jj * 1024);
  float a0 = 0.f, a1 = 0.f;
  #pragma unroll 4
  for (int k0 = 0; k0 < 512; k0 += 8) {
    s16x8 wv = *(const s16x8*)(col + k0);
    #pragma unroll
    for (int r = 0; r < 8; ++r) a0 += hl[k0 + r] * bf2f((ushort_t)wv[r]);
  }
  #pragma unroll 4
  for (int k0 = 512; k0 < 1024; k0 += 8) {
    s16x8 wv = *(const s16x8*)(col + k0);
    #pragma unroll
    for (int r = 0; r < 8; ++r) a1 += hl[k0 + r] * bf2f((ushort_t)wv[r]);
  }
  if (g < 3) exch[g][jc] = a0 + a1;
  else { exch[3][jc] = a0; exch[4][jc] = a1; }
  __syncthreads();

  if (tid < 64) {
    int j = j0 + tid;
    float ai = exch[0][tid], ao = exch[1][tid], au = exch[2][tid];
    float af0 = exch[3][tid], af1 = exch[4][tid];
    int tok = tokens[node0 + i];
    const float* Wr = Wiou + (size_t)tok * 1536;
    float fpre = Wf[(size_t)tok * 512 + j] + bf[j];
    float ig = ai + Wr[j] + biou[j];
    float og = ao + Wr[512 + j] + biou[512 + j];
    float ug = au + Wr[1024 + j] + biou[1024 + j];
    float cc = sigm(ig) * ftanh(ug)
             + sigm(fpre + af0) * cprev[(size_t)(2 * i) * 512 + j]
             + sigm(fpre + af1) * cprev[(size_t)(2 * i + 1) * 512 + j];
    float hh = sigm(og) * ftanh(cc);
    hout[(size_t)i * 512 + j] = f2bf(hh);
    cout[(size_t)i * 512 + j] = cc;
  }
}

// ---------------- root ternary cell: 2-phase k-split -----------------------
__global__ __launch_bounds__(256) void k_root_p1() {
  const int by = blockIdx.y;
  const int tid = threadIdx.x;
  const int c = blockIdx.x * 256 + tid;      // 0..3071

  __shared__ float hl[512];
  {
    int m0 = by * 512;
    #pragma unroll
    for (int q = 0; q < 2; ++q) {
      int t = tid + q * 256, m = m0 + t;
      hl[t] = (m < 512) ? bf2f(g_hb0[m]) : bf2f(g_hb1[m - 512]);
    }
  }
  __syncthreads();

  float acc = 0.f;
  const ushort_t* col = nullptr;
  if (c < 1536) {
    col = g_UiouTt + (size_t)c * 1536 + by * 512;
  } else {
    int v = c - 1536;
    if ((v >> 9) == by) col = g_UfTt + (size_t)(v & 511) * 1536 + by * 512;
  }
  if (col) {
    #pragma unroll 4
    for (int k0 = 0; k0 < 512; k0 += 8) {
      s16x8 wv = *(const s16x8*)(col + k0);
      #pragma unroll
      for (int r = 0; r < 8; ++r) acc += hl[k0 + r] * bf2f((ushort_t)wv[r]);
    }
  }
  g_rpart[(size_t)by * 3072 + c] = acc;
}

// ---------------- root phase 2 + FFN head, single block --------------------
__global__ __launch_bounds__(512) void k_p2h1(const int* __restrict__ tokens,
    const float* __restrict__ Wiou_t, const float* __restrict__ biou_t,
    const float* __restrict__ Wf_t, const float* __restrict__ bf_t,
    const float* __restrict__ ffnW, const float* __restrict__ ffnb) {
  __shared__ float hroot[H];
  const int j = threadIdx.x;
  float ai = g_rpart[j] + g_rpart[3072 + j] + g_rpart[6144 + j];
  float ao = g_rpart[512 + j] + g_rpart[3072 + 512 + j] + g_rpart[6144 + 512 + j];
  float au = g_rpart[1024 + j] + g_rpart[3072 + 1024 + j] + g_rpart[6144 + 1024 + j];
  float f0 = g_rpart[1536 + j] + g_rpart[3072 + 1536 + j] + g_rpart[6144 + 1536 + j];
  float f1 = g_rpart[2048 + j] + g_rpart[3072 + 2048 + j] + g_rpart[6144 + 2048 + j];
  float f2 = g_rpart[2560 + j] + g_rpart[3072 + 2560 + j] + g_rpart[6144 + 2560 + j];

  int tok = tokens[0];
  float fpre = Wf_t[(size_t)tok * H + j] + bf_t[j];
  float ig = ai + Wiou_t[(size_t)tok * 3 * H + j] + biou_t[j];
  float og = ao + Wiou_t[(size_t)tok * 3 * H + H + j] + biou_t[H + j];
  float ug = au + Wiou_t[(size_t)tok * 3 * H + 2 * H + j] + biou_t[2 * H + j];
  float cc = sigm(ig) * ftanh(ug)
           + sigm(fpre + f0) * g_c0[j]
           + sigm(fpre + f1) * g_c1[j]
           + sigm(fpre + f2) * g_c1[H + j];
  hroot[j] = sigm(og) * ftanh(cc);
  __syncthreads();

  float acc = ffnb[j];
  #pragma unroll 8
  for (int m = 0; m < H; ++m) acc += hroot[m] * ffnW[m * H + j];
  g_hf[j] = fmaxf(acc, 0.0f);
}

// ---------------- head2: only the 1536 live gates (gf dead: c_g=0) ---------
__global__ __launch_bounds__(64) void k_head2(const float* __restrict__ Wx,
                                              const float* __restrict__ lb) {
  int idx = blockIdx.x * 64 + threadIdx.x;   // 0..1535
  int region = idx >> 9;                      // 0 gi, 1 gg, 2 go
  int j = idx & 511;
  int g2 = (region == 0) ? j : ((region == 1) ? 1024 + j : 1536 + j);
  float acc = lb[g2];
  #pragma unroll 8
  for (int m = 0; m < H; ++m) acc += g_hf[m] * Wx[m * 4 * H + g2];
  g_gates[g2] = acc;  // h_g starts at 0 so Wh term vanishes
}

__global__ __launch_bounds__(512) void k_head3(const float* __restrict__ vm,
    const float* __restrict__ hlW, const float* __restrict__ hlb,
    const float* __restrict__ intW, const float* __restrict__ intb,
    const float* __restrict__ actW, const float* __restrict__ actb,
    float* __restrict__ out) {
  __shared__ float feat[2 * H];
  int j = threadIdx.x;
  float ci = sigm(g_gates[j]) * ftanh(g_gates[2 * H + j]);
  float hg = sigm(g_gates[3 * H + j]) * ftanh(ci);
  feat[j] = g_hf[j];
  feat[H + j] = hg;
  __syncthreads();

  const int wv = threadIdx.x >> 6;
  const int lane = threadIdx.x & 63;
  for (int o = wv; o < 43; o += 8) {
    const float* Wc;
    int stride, colb;
    if (o < 2)       { Wc = hlW;  stride = 2;  colb = o; }
    else if (o < 7)  { Wc = intW; stride = 5;  colb = o - 2; }
    else             { Wc = actW; stride = 36; colb = o - 7; }
    float s = 0.f;
    #pragma unroll
    for (int q = 0; q < 16; ++q) {
      int m = lane + q * 64;
      s += feat[m] * Wc[(size_t)m * stride + colb];
    }
    #pragma unroll
    for (int d = 32; d >= 1; d >>= 1) s += __shfl_xor(s, d);
    if (lane == 0) {
      float res;
      if (o < 2)      res = s + hlb[o];
      else if (o < 7) res = s + intb[o - 2];
      else {
        int a = o - 7;
        float v = vm[a];
        res = __logf(v) + s * v + actb[a] * v;
      }
      out[o] = res;
    }
  }
}

extern "C" void kernel_launch(void* const* d_in, const int* in_sizes, int n_in,
                              void* d_out, int out_size, void* d_ws, size_t ws_size,
                              hipStream_t stream) {
  (void)in_sizes; (void)n_in; (void)d_ws; (void)ws_size; (void)out_size;
  const int* tokens   = (const int*)d_in[0];
  const float* vm     = (const float*)d_in[1];
  const float* Wiou_b = (const float*)d_in[2];
  const float* Uiou_b = (const float*)d_in[3];
  const float* biou_b = (const float*)d_in[4];
  const float* Wf_b   = (const float*)d_in[5];
  const float* Uf_b   = (const float*)d_in[6];
  const float* bf_b   = (const float*)d_in[7];
  const float* Wiou_t = (const float*)d_in[8];
  const float* Uiou_t = (const float*)d_in[9];
  const float* biou_t = (const float*)d_in[10];
  const float* Wf_t   = (const float*)d_in[11];
  const float* Uf_t   = (const float*)d_in[12];
  const float* bf_t   = (const float*)d_in[13];
  const float* ffnW   = (const float*)d_in[14];
  const float* ffnb   = (const float*)d_in[15];
  const float* lstmWx = (const float*)d_in[16];
  const float* lstmb  = (const float*)d_in[18];
  const float* hlW    = (const float*)d_in[19];
  const float* hlb    = (const float*)d_in[20];
  const float* intW   = (const float*)d_in[21];
  const float* intb   = (const float*)d_in[22];
  const float* actW   = (const float*)d_in[23];
  const float* actb   = (const float*)d_in[24];

  ushort_t* UiouT;  hipGetSymbolAddress((void**)&UiouT, HIP_SYMBOL(g_UiouT));
  ushort_t* UfT;    hipGetSymbolAddress((void**)&UfT, HIP_SYMBOL(g_UfT));
  ushort_t* UiouTt; hipGetSymbolAddress((void**)&UiouTt, HIP_SYMBOL(g_UiouTt));
  ushort_t* UfTt;   hipGetSymbolAddress((void**)&UfTt, HIP_SYMBOL(g_UfTt));

  // transposes + leaf in one launch
  k_prep<<<dim3(48, 48, 5), 256, 0, stream>>>(
      Uiou_b, Uf_b, Uiou_t, Uf_t, UiouT, UfT, UiouTt, UfTt,
      tokens, Wiou_b, biou_b);

  for (int lvl = 13; lvl >= 8; --lvl) {
    int nb = ((1 << lvl) / 128) * 8;
    k_mfma_lvl<<<nb, 256, 0, stream>>>(lvl, tokens, Wiou_b, biou_b,
                                       Wf_b, bf_b);
  }
  for (int lvl = 7; lvl >= 0; --lvl) {
    int n = 1 << lvl;
    k_small<<<dim3(8, n), 256, 0, stream>>>(lvl, tokens, Wiou_b, biou_b,
                                            Wf_b, bf_b);
  }
  k_root_p1<<<dim3(12, 3), 256, 0, stream>>>();
  k_p2h1<<<1, 512, 0, stream>>>(tokens, Wiou_t, biou_t, Wf_t, bf_t, ffnW, ffnb);
  k_head2<<<24, 64, 0, stream>>>(lstmWx, lstmb);
  k_head3<<<1, 512, 0, stream>>>(vm, hlW, hlb, intW, intb, actW, actb, (float*)d_out);
}

// Round 10
// 670.549 us; speedup vs baseline: 2.1716x; 2.1716x over previous
//
#include <hip/hip_runtime.h>
#include <hip/hip_bf16.h>
#include <math.h>

#define H 512
#define V 128
#define NLEAF 16384

typedef __attribute__((ext_vector_type(4))) float f32x4;
typedef __attribute__((ext_vector_type(8))) short s16x8;
typedef __attribute__((ext_vector_type(4))) unsigned short u16x4;
typedef unsigned short ushort_t;

// ---- static device scratch ----
__device__ ushort_t g_hb0[NLEAF * H];        // h bf16 (levels 14,12,...,0)
__device__ ushort_t g_hb1[(NLEAF / 2) * H];  // h bf16 (levels 13,11,...,1)
__device__ float    g_c0[NLEAF * H];         // c f32
__device__ float    g_c1[(NLEAF / 2) * H];
__device__ ushort_t g_UiouT[3 * H * 2 * H];  // [1536 cols][1024 k] bf16 (binary)
__device__ ushort_t g_UfT[H * 2 * H];        // [512 cols][1024 k] bf16 (f0|f1 halves)
__device__ ushort_t g_UiouTt[3 * H * 3 * H]; // [1536 cols][1536 k] bf16 (root)
__device__ ushort_t g_UfTt[H * 3 * H];       // [512 cols][1536 k] bf16 (f0|f1|f2)
__device__ float    g_rpart[3 * 3072];       // root k-chunk partials
__device__ float    g_hf[H];
__device__ float    g_gates[4 * H];

__device__ __forceinline__ float sigm(float x) { return 1.0f / (1.0f + __expf(-x)); }
__device__ __forceinline__ float ftanh(float x) {
  return 1.0f - 2.0f / (__expf(2.0f * x) + 1.0f);
}
__device__ __forceinline__ ushort_t f2bf(float x) {
  __hip_bfloat16 b = __float2bfloat16(x);
  return *reinterpret_cast<ushort_t*>(&b);
}
__device__ __forceinline__ float bf2f(ushort_t u) {
  union { unsigned int i; float f; } v; v.i = ((unsigned int)u) << 16; return v.f;
}
__device__ __forceinline__ void gload_lds16(const void* g, void* l) {
  __builtin_amdgcn_global_load_lds(
      (const __attribute__((address_space(1))) unsigned int*)g,
      (__attribute__((address_space(3))) unsigned int*)l, 16, 0, 0);
}

// ---------------- prep: 4 weight transposes (z<4) + leaf level (z==4) ------
__global__ __launch_bounds__(256) void k_prep(
    const float* __restrict__ s0, const float* __restrict__ s1,
    const float* __restrict__ s2, const float* __restrict__ s3,
    ushort_t* __restrict__ d0, ushort_t* __restrict__ d1,
    ushort_t* __restrict__ d2, ushort_t* __restrict__ d3,
    const int* __restrict__ tokens,
    const float* __restrict__ Wiou, const float* __restrict__ biou) {
  if (blockIdx.z == 4) {                     // ---- leaf (lvl 14) ----
    const int total = NLEAF * 128;           // quads
    const int bid = blockIdx.y * 48 + blockIdx.x;
    for (int q = bid * 256 + threadIdx.x; q < total; q += 2304 * 256) {
      int i = q >> 7, jv = q & 127;
      int tok = tokens[(NLEAF - 1) + i];
      const f32x4* Wr = (const f32x4*)(Wiou + (size_t)tok * 1536);
      const f32x4* bv = (const f32x4*)biou;
      f32x4 wi = Wr[jv] + bv[jv];
      f32x4 wo = Wr[128 + jv] + bv[128 + jv];
      f32x4 wu = Wr[256 + jv] + bv[256 + jv];
      u16x4 hv; f32x4 cv;
      #pragma unroll
      for (int r = 0; r < 4; ++r) {
        float c = sigm(wi[r]) * ftanh(wu[r]);
        float h = sigm(wo[r]) * ftanh(c);
        cv[r] = c;
        hv[r] = f2bf(h);
      }
      *reinterpret_cast<u16x4*>(&g_hb0[(size_t)q * 4]) = hv;
      *reinterpret_cast<f32x4*>(&g_c0[(size_t)q * 4]) = cv;
    }
    return;
  }
  // ---- transpose+bf16: dst[c][r] = bf16(src[r][c]) ----
  const float* src; ushort_t* dst; int R, Cc;
  switch (blockIdx.z) {
    case 0: src = s0; dst = d0; R = 1024; Cc = 1536; break;
    case 1: src = s1; dst = d1; R = 1024; Cc = 512; break;
    case 2: src = s2; dst = d2; R = 1536; Cc = 1536; break;
    default: src = s3; dst = d3; R = 1536; Cc = 512; break;
  }
  int bc = blockIdx.x * 32, br = blockIdx.y * 32;
  if (bc >= Cc || br >= R) return;
  __shared__ float t[32][33];
  int tx = threadIdx.x & 31, ty = threadIdx.x >> 5;
  for (int rr = ty; rr < 32; rr += 8)
    t[rr][tx] = src[(size_t)(br + rr) * Cc + bc + tx];
  __syncthreads();
  for (int rr = ty; rr < 32; rr += 8)
    dst[(size_t)(bc + rr) * R + br + tx] = f2bf(t[tx][rr]);
}

// ---------------- big levels: MFMA bf16 fused cell (shared body) -----------
// 256 thr = 4 waves (2 row x 2 col). Tile: 128 nodes x 64 j-cols x 5 gates.
// Depth-2 counted-vmcnt pipeline, 48KB LDS, 2 blocks/CU (register-locked).
__device__ __forceinline__ void mfma_body(int lvl,
    const int* __restrict__ tokens,
    const float* __restrict__ Wiou, const float* __restrict__ biou,
    const float* __restrict__ Wf, const float* __restrict__ bf) {
  const int n = 1 << lvl;
  const int node0 = n - 1;
  const int outp = lvl & 1;
  const ushort_t* __restrict__ hprev = outp ? g_hb0 : g_hb1;
  const float* __restrict__ cprev = outp ? g_c0 : g_c1;
  ushort_t* __restrict__ hout = outp ? g_hb1 : g_hb0;
  float* __restrict__ cout = outp ? g_c1 : g_c0;

  // XCD-chunked bijective swizzle (grid size always % 8 == 0 here)
  const int orig = blockIdx.x;
  const int qch = gridDim.x >> 3;
  const int wg = (orig & 7) * qch + (orig >> 3);
  const int i0 = (wg >> 3) * 128;
  const int j0 = (wg & 7) * 64;

  const int tid = threadIdx.x;
  const int lane = tid & 63;
  const int w = tid >> 6;        // 0..3
  const int wry = w >> 1;        // row half
  const int cx = w & 1;          // col half

  __shared__ f32x4 smemv[3072];  // 48KB: A 2x8KB @0, B 2x16KB @16384
  char* smem = (char*)smemv;

  const char* gp[6];
  unsigned lb[6], lstride[6];
  {
    int kb = (lane >> 4) * 16;
    #pragma unroll
    for (int q = 0; q < 6; ++q) {
      int c = w * 6 + q;
      if (c < 8) {               // A chunk, row-tile c
        int row = i0 + c * 16 + (lane & 15);
        gp[q] = (const char*)hprev + (size_t)row * 2048 + kb;
        lb[q] = c * 1024u;
        lstride[q] = 8192u;
      } else {                   // B chunk, col-tile ct
        int ct = c - 8;
        int col = ct * 16 + (lane & 15);
        int g = col >> 6, jj = j0 + (col & 63);
        const ushort_t* Ub = (g < 3) ? (g_UiouT + (size_t)(g * 512 + jj) * 1024)
                                     : (g_UfT + (size_t)jj * 1024);
        gp[q] = (const char*)Ub + kb;
        lb[q] = 16384u + ct * 1024u;
        lstride[q] = 16384u;
      }
    }
  }

#define STAGE(BUF)                                                   \
  {                                                                  \
    _Pragma("unroll")                                                \
    for (int q = 0; q < 6; ++q) {                                    \
      gload_lds16(gp[q], smem + lb[q] + (unsigned)(BUF) * lstride[q]); \
      gp[q] += 64;                                                   \
    }                                                                \
  }
#define WAITV(N) asm volatile("s_waitcnt vmcnt(" #N ")" ::: "memory")

  f32x4 acc[4][10];
  #pragma unroll
  for (int a = 0; a < 4; ++a)
    #pragma unroll
    for (int b = 0; b < 10; ++b) acc[a][b] = (f32x4){0.f, 0.f, 0.f, 0.f};

#define COMPUTE(FA)                                                          \
  {                                                                          \
    const char* ab = smem + buf * 8192 + wry * 4096 + lane * 16;             \
    s16x8 a0 = *(const s16x8*)(ab);                                          \
    s16x8 a1 = *(const s16x8*)(ab + 1024);                                   \
    s16x8 a2 = *(const s16x8*)(ab + 2048);                                   \
    s16x8 a3 = *(const s16x8*)(ab + 3072);                                   \
    const char* bb = smem + 16384 + buf * 16384 + cx * 2048 + lane * 16;     \
    s16x8 b0 = *(const s16x8*)(bb);                                          \
    s16x8 b1 = *(const s16x8*)(bb + 1024);                                   \
    s16x8 b2 = *(const s16x8*)(bb + 4096);                                   \
    s16x8 b3 = *(const s16x8*)(bb + 5120);                                   \
    s16x8 b4 = *(const s16x8*)(bb + 8192);                                   \
    s16x8 b5 = *(const s16x8*)(bb + 9216);                                   \
    s16x8 b6 = *(const s16x8*)(bb + 12288);                                  \
    s16x8 b7 = *(const s16x8*)(bb + 13312);                                  \
    s16x8 aa[4] = {a0, a1, a2, a3};                                          \
    _Pragma("unroll")                                                        \
    for (int rtl = 0; rtl < 4; ++rtl) {                                      \
      acc[rtl][0] = __builtin_amdgcn_mfma_f32_16x16x32_bf16(aa[rtl], b0, acc[rtl][0], 0, 0, 0); \
      acc[rtl][1] = __builtin_amdgcn_mfma_f32_16x16x32_bf16(aa[rtl], b1, acc[rtl][1], 0, 0, 0); \
      acc[rtl][2] = __builtin_amdgcn_mfma_f32_16x16x32_bf16(aa[rtl], b2, acc[rtl][2], 0, 0, 0); \
      acc[rtl][3] = __builtin_amdgcn_mfma_f32_16x16x32_bf16(aa[rtl], b3, acc[rtl][3], 0, 0, 0); \
      acc[rtl][4] = __builtin_amdgcn_mfma_f32_16x16x32_bf16(aa[rtl], b4, acc[rtl][4], 0, 0, 0); \
      acc[rtl][5] = __builtin_amdgcn_mfma_f32_16x16x32_bf16(aa[rtl], b5, acc[rtl][5], 0, 0, 0); \
      acc[rtl][FA] = __builtin_amdgcn_mfma_f32_16x16x32_bf16(aa[rtl], b6, acc[rtl][FA], 0, 0, 0); \
      acc[rtl][FA + 1] = __builtin_amdgcn_mfma_f32_16x16x32_bf16(aa[rtl], b7, acc[rtl][FA + 1], 0, 0, 0); \
    }                                                                        \
  }

  STAGE(0); STAGE(1);
  int buf = 0;
  for (int kt = 0; kt < 16; ++kt) {
    WAITV(6);
    __builtin_amdgcn_s_barrier();
    COMPUTE(6);
    __builtin_amdgcn_s_barrier();
    STAGE(buf);
    buf ^= 1;
  }
  for (int kt = 16; kt < 30; ++kt) {
    WAITV(6);
    __builtin_amdgcn_s_barrier();
    COMPUTE(8);
    __builtin_amdgcn_s_barrier();
    STAGE(buf);
    buf ^= 1;
  }
  WAITV(6); __builtin_amdgcn_s_barrier(); COMPUTE(8); buf ^= 1;
  WAITV(0); __builtin_amdgcn_s_barrier(); COMPUTE(8);
#undef COMPUTE
#undef STAGE
#undef WAITV

  const int node_c = lane >> 4;
  const int jl = lane & 15;
  #pragma unroll
  for (int t = 0; t < 2; ++t) {
    const int j = j0 + cx * 32 + t * 16 + jl;
    const float bi = biou[j], bo = biou[512 + j], bu = biou[1024 + j], bfv = bf[j];
    #pragma unroll
    for (int rtl = 0; rtl < 4; ++rtl) {
      f32x4 vi = acc[rtl][0 + t], vo = acc[rtl][2 + t], vu = acc[rtl][4 + t],
            v0 = acc[rtl][6 + t], v1 = acc[rtl][8 + t];
      const int ib = i0 + wry * 64 + rtl * 16 + node_c * 4;
      #pragma unroll
      for (int r = 0; r < 4; ++r) {
        int i = ib + r;
        int tok = tokens[node0 + i];
        const float* Wr = Wiou + (size_t)tok * 1536;
        float fpre = Wf[(size_t)tok * 512 + j] + bfv;
        float ig = vi[r] + Wr[j] + bi;
        float og = vo[r] + Wr[512 + j] + bo;
        float ug = vu[r] + Wr[1024 + j] + bu;
        float cc = sigm(ig) * ftanh(ug)
                 + sigm(fpre + v0[r]) * cprev[(size_t)(2 * i) * 512 + j]
                 + sigm(fpre + v1[r]) * cprev[(size_t)(2 * i + 1) * 512 + j];
        float hh = sigm(og) * ftanh(cc);
        hout[(size_t)i * 512 + j] = f2bf(hh);
        cout[(size_t)i * 512 + j] = cc;
      }
    }
  }
}

// two symbols for per-level profiling visibility (identical body)
__global__ __launch_bounds__(256, 2) void k_mfma_top(
    const int* __restrict__ tokens,
    const float* __restrict__ Wiou, const float* __restrict__ biou,
    const float* __restrict__ Wf, const float* __restrict__ bf) {
  mfma_body(13, tokens, Wiou, biou, Wf, bf);
}
__global__ __launch_bounds__(256, 2) void k_mfma_rest(int lvl,
    const int* __restrict__ tokens,
    const float* __restrict__ Wiou, const float* __restrict__ biou,
    const float* __restrict__ Wf, const float* __restrict__ bf) {
  mfma_body(lvl, tokens, Wiou, biou, Wf, bf);
}

// ------------- small levels (n <= 128): single fused GEMV kernel -----------
__global__ __launch_bounds__(256) void k_small(int lvl,
    const int* __restrict__ tokens,
    const float* __restrict__ Wiou, const float* __restrict__ biou,
    const float* __restrict__ Wf, const float* __restrict__ bf) {
  const int n = 1 << lvl;
  const int node0 = n - 1;
  const int outp = lvl & 1;
  const ushort_t* __restrict__ hprev = outp ? g_hb0 : g_hb1;
  const float* __restrict__ cprev = outp ? g_c0 : g_c1;
  ushort_t* __restrict__ hout = outp ? g_hb1 : g_hb0;
  float* __restrict__ cout = outp ? g_c1 : g_c0;

  const int i = blockIdx.y;
  const int j0 = blockIdx.x * 64;
  const int tid = threadIdx.x;
  const int g = tid >> 6;
  const int jc = tid & 63;
  const int jj = j0 + jc;

  __shared__ float hl[1024];
  __shared__ float exch[5][64];
  for (int t = tid; t < 1024; t += 256) hl[t] = bf2f(hprev[(size_t)i * 1024 + t]);
  __syncthreads();

  const ushort_t* col = (g < 3) ? (g_UiouT + (size_t)(g * 512 + jj) * 1024)
                                : (g_UfT + (size_t)jj * 1024);
  float a0 = 0.f, a1 = 0.f;
  #pragma unroll 4
  for (int k0 = 0; k0 < 512; k0 += 8) {
    s16x8 wv = *(const s16x8*)(col + k0);
    #pragma unroll
    for (int r = 0; r < 8; ++r) a0 += hl[k0 + r] * bf2f((ushort_t)wv[r]);
  }
  #pragma unroll 4
  for (int k0 = 512; k0 < 1024; k0 += 8) {
    s16x8 wv = *(const s16x8*)(col + k0);
    #pragma unroll
    for (int r = 0; r < 8; ++r) a1 += hl[k0 + r] * bf2f((ushort_t)wv[r]);
  }
  if (g < 3) exch[g][jc] = a0 + a1;
  else { exch[3][jc] = a0; exch[4][jc] = a1; }
  __syncthreads();

  if (tid < 64) {
    int j = j0 + tid;
    float ai = exch[0][tid], ao = exch[1][tid], au = exch[2][tid];
    float af0 = exch[3][tid], af1 = exch[4][tid];
    int tok = tokens[node0 + i];
    const float* Wr = Wiou + (size_t)tok * 1536;
    float fpre = Wf[(size_t)tok * 512 + j] + bf[j];
    float ig = ai + Wr[j] + biou[j];
    float og = ao + Wr[512 + j] + biou[512 + j];
    float ug = au + Wr[1024 + j] + biou[1024 + j];
    float cc = sigm(ig) * ftanh(ug)
             + sigm(fpre + af0) * cprev[(size_t)(2 * i) * 512 + j]
             + sigm(fpre + af1) * cprev[(size_t)(2 * i + 1) * 512 + j];
    float hh = sigm(og) * ftanh(cc);
    hout[(size_t)i * 512 + j] = f2bf(hh);
    cout[(size_t)i * 512 + j] = cc;
  }
}

// ---------------- root ternary cell: 2-phase k-split -----------------------
__global__ __launch_bounds__(256) void k_root_p1() {
  const int by = blockIdx.y;
  const int tid = threadIdx.x;
  const int c = blockIdx.x * 256 + tid;      // 0..3071

  __shared__ float hl[512];
  {
    int m0 = by * 512;
    #pragma unroll
    for (int q = 0; q < 2; ++q) {
      int t = tid + q * 256, m = m0 + t;
      hl[t] = (m < 512) ? bf2f(g_hb0[m]) : bf2f(g_hb1[m - 512]);
    }
  }
  __syncthreads();

  float acc = 0.f;
  const ushort_t* col = nullptr;
  if (c < 1536) {
    col = g_UiouTt + (size_t)c * 1536 + by * 512;
  } else {
    int v = c - 1536;
    if ((v >> 9) == by) col = g_UfTt + (size_t)(v & 511) * 1536 + by * 512;
  }
  if (col) {
    #pragma unroll 4
    for (int k0 = 0; k0 < 512; k0 += 8) {
      s16x8 wv = *(const s16x8*)(col + k0);
      #pragma unroll
      for (int r = 0; r < 8; ++r) acc += hl[k0 + r] * bf2f((ushort_t)wv[r]);
    }
  }
  g_rpart[(size_t)by * 3072 + c] = acc;
}

// ---------------- root phase 2 + FFN head, single block --------------------
__global__ __launch_bounds__(512) void k_p2h1(const int* __restrict__ tokens,
    const float* __restrict__ Wiou_t, const float* __restrict__ biou_t,
    const float* __restrict__ Wf_t, const float* __restrict__ bf_t,
    const float* __restrict__ ffnW, const float* __restrict__ ffnb) {
  __shared__ float hroot[H];
  const int j = threadIdx.x;
  float ai = g_rpart[j] + g_rpart[3072 + j] + g_rpart[6144 + j];
  float ao = g_rpart[512 + j] + g_rpart[3072 + 512 + j] + g_rpart[6144 + 512 + j];
  float au = g_rpart[1024 + j] + g_rpart[3072 + 1024 + j] + g_rpart[6144 + 1024 + j];
  float f0 = g_rpart[1536 + j] + g_rpart[3072 + 1536 + j] + g_rpart[6144 + 1536 + j];
  float f1 = g_rpart[2048 + j] + g_rpart[3072 + 2048 + j] + g_rpart[6144 + 2048 + j];
  float f2 = g_rpart[2560 + j] + g_rpart[3072 + 2560 + j] + g_rpart[6144 + 2560 + j];

  int tok = tokens[0];
  float fpre = Wf_t[(size_t)tok * H + j] + bf_t[j];
  float ig = ai + Wiou_t[(size_t)tok * 3 * H + j] + biou_t[j];
  float og = ao + Wiou_t[(size_t)tok * 3 * H + H + j] + biou_t[H + j];
  float ug = au + Wiou_t[(size_t)tok * 3 * H + 2 * H + j] + biou_t[2 * H + j];
  float cc = sigm(ig) * ftanh(ug)
           + sigm(fpre + f0) * g_c0[j]
           + sigm(fpre + f1) * g_c1[j]
           + sigm(fpre + f2) * g_c1[H + j];
  hroot[j] = sigm(og) * ftanh(cc);
  __syncthreads();

  float acc = ffnb[j];
  #pragma unroll 8
  for (int m = 0; m < H; ++m) acc += hroot[m] * ffnW[m * H + j];
  g_hf[j] = fmaxf(acc, 0.0f);
}

// ---------------- head2: only the 1536 live gates (gf dead: c_g=0) ---------
__global__ __launch_bounds__(64) void k_head2(const float* __restrict__ Wx,
                                              const float* __restrict__ lb) {
  int idx = blockIdx.x * 64 + threadIdx.x;   // 0..1535
  int region = idx >> 9;                      // 0 gi, 1 gg, 2 go
  int j = idx & 511;
  int g2 = (region == 0) ? j : ((region == 1) ? 1024 + j : 1536 + j);
  float acc = lb[g2];
  #pragma unroll 8
  for (int m = 0; m < H; ++m) acc += g_hf[m] * Wx[m * 4 * H + g2];
  g_gates[g2] = acc;  // h_g starts at 0 so Wh term vanishes
}

__global__ __launch_bounds__(512) void k_head3(const float* __restrict__ vm,
    const float* __restrict__ hlW, const float* __restrict__ hlb,
    const float* __restrict__ intW, const float* __restrict__ intb,
    const float* __restrict__ actW, const float* __restrict__ actb,
    float* __restrict__ out) {
  __shared__ float feat[2 * H];
  int j = threadIdx.x;
  float ci = sigm(g_gates[j]) * ftanh(g_gates[2 * H + j]);
  float hg = sigm(g_gates[3 * H + j]) * ftanh(ci);
  feat[j] = g_hf[j];
  feat[H + j] = hg;
  __syncthreads();

  const int wv = threadIdx.x >> 6;
  const int lane = threadIdx.x & 63;
  for (int o = wv; o < 43; o += 8) {
    const float* Wc;
    int stride, colb;
    if (o < 2)       { Wc = hlW;  stride = 2;  colb = o; }
    else if (o < 7)  { Wc = intW; stride = 5;  colb = o - 2; }
    else             { Wc = actW; stride = 36; colb = o - 7; }
    float s = 0.f;
    #pragma unroll
    for (int q = 0; q < 16; ++q) {
      int m = lane + q * 64;
      s += feat[m] * Wc[(size_t)m * stride + colb];
    }
    #pragma unroll
    for (int d = 32; d >= 1; d >>= 1) s += __shfl_xor(s, d);
    if (lane == 0) {
      float res;
      if (o < 2)      res = s + hlb[o];
      else if (o < 7) res = s + intb[o - 2];
      else {
        int a = o - 7;
        float v = vm[a];
        res = __logf(v) + s * v + actb[a] * v;
      }
      out[o] = res;
    }
  }
}

extern "C" void kernel_launch(void* const* d_in, const int* in_sizes, int n_in,
                              void* d_out, int out_size, void* d_ws, size_t ws_size,
                              hipStream_t stream) {
  (void)in_sizes; (void)n_in; (void)d_ws; (void)ws_size; (void)out_size;
  const int* tokens   = (const int*)d_in[0];
  const float* vm     = (const float*)d_in[1];
  const float* Wiou_b = (const float*)d_in[2];
  const float* Uiou_b = (const float*)d_in[3];
  const float* biou_b = (const float*)d_in[4];
  const float* Wf_b   = (const float*)d_in[5];
  const float* Uf_b   = (const float*)d_in[6];
  const float* bf_b   = (const float*)d_in[7];
  const float* Wiou_t = (const float*)d_in[8];
  const float* Uiou_t = (const float*)d_in[9];
  const float* biou_t = (const float*)d_in[10];
  const float* Wf_t   = (const float*)d_in[11];
  const float* Uf_t   = (const float*)d_in[12];
  const float* bf_t   = (const float*)d_in[13];
  const float* ffnW   = (const float*)d_in[14];
  const float* ffnb   = (const float*)d_in[15];
  const float* lstmWx = (const float*)d_in[16];
  const float* lstmb  = (const float*)d_in[18];
  const float* hlW    = (const float*)d_in[19];
  const float* hlb    = (const float*)d_in[20];
  const float* intW   = (const float*)d_in[21];
  const float* intb   = (const float*)d_in[22];
  const float* actW   = (const float*)d_in[23];
  const float* actb   = (const float*)d_in[24];

  ushort_t* UiouT;  hipGetSymbolAddress((void**)&UiouT, HIP_SYMBOL(g_UiouT));
  ushort_t* UfT;    hipGetSymbolAddress((void**)&UfT, HIP_SYMBOL(g_UfT));
  ushort_t* UiouTt; hipGetSymbolAddress((void**)&UiouTt, HIP_SYMBOL(g_UiouTt));
  ushort_t* UfTt;   hipGetSymbolAddress((void**)&UfTt, HIP_SYMBOL(g_UfTt));

  // transposes + leaf in one launch
  k_prep<<<dim3(48, 48, 5), 256, 0, stream>>>(
      Uiou_b, Uf_b, Uiou_t, Uf_t, UiouT, UfT, UiouTt, UfTt,
      tokens, Wiou_b, biou_b);

  k_mfma_top<<<512, 256, 0, stream>>>(tokens, Wiou_b, biou_b, Wf_b, bf_b);
  for (int lvl = 12; lvl >= 8; --lvl) {
    int nb = ((1 << lvl) / 128) * 8;
    k_mfma_rest<<<nb, 256, 0, stream>>>(lvl, tokens, Wiou_b, biou_b,
                                        Wf_b, bf_b);
  }
  for (int lvl = 7; lvl >= 0; --lvl) {
    int n = 1 << lvl;
    k_small<<<dim3(8, n), 256, 0, stream>>>(lvl, tokens, Wiou_b, biou_b,
                                            Wf_b, bf_b);
  }
  k_root_p1<<<dim3(12, 3), 256, 0, stream>>>();
  k_p2h1<<<1, 512, 0, stream>>>(tokens, Wiou_t, biou_t, Wf_t, bf_t, ffnW, ffnb);
  k_head2<<<24, 64, 0, stream>>>(lstmWx, lstmb);
  k_head3<<<1, 512, 0, stream>>>(vm, hlW, hlb, intW, intb, actW, actb, (float*)d_out);
}

// Round 11
// 584.741 us; speedup vs baseline: 2.4903x; 1.1467x over previous
//
#include <hip/hip_runtime.h>
#include <hip/hip_bf16.h>
#include <math.h>

#define H 512
#define V 128
#define NLEAF 16384

typedef __attribute__((ext_vector_type(4))) float f32x4;
typedef __attribute__((ext_vector_type(8))) short s16x8;
typedef unsigned short ushort_t;

// ---- static device scratch ----
__device__ ushort_t g_hb0[NLEAF * H];        // h bf16 (levels 12,10,...,0)
__device__ ushort_t g_hb1[(NLEAF / 2) * H];  // h bf16 (levels 13,11,...,1)
__device__ float    g_c0[NLEAF * H];         // c f32
__device__ float    g_c1[(NLEAF / 2) * H];
__device__ __align__(16) ushort_t g_htab[V * H];  // leaf h by token (128KB)
__device__ __align__(16) float    g_ctab[V * H];  // leaf c by token (256KB)
__device__ ushort_t g_UiouT[3 * H * 2 * H];  // [1536 cols][1024 k] bf16 (binary)
__device__ ushort_t g_UfT[H * 2 * H];        // [512 cols][1024 k] bf16 (f0|f1 halves)
__device__ ushort_t g_UiouTt[3 * H * 3 * H]; // [1536 cols][1536 k] bf16 (root)
__device__ ushort_t g_UfTt[H * 3 * H];       // [512 cols][1536 k] bf16 (f0|f1|f2)
__device__ float    g_rpart[3 * 3072];       // root k-chunk partials
__device__ float    g_hf[H];
__device__ float    g_gates[4 * H];

__device__ __forceinline__ float sigm(float x) { return 1.0f / (1.0f + __expf(-x)); }
__device__ __forceinline__ float ftanh(float x) {
  return 1.0f - 2.0f / (__expf(2.0f * x) + 1.0f);
}
__device__ __forceinline__ ushort_t f2bf(float x) {
  __hip_bfloat16 b = __float2bfloat16(x);
  return *reinterpret_cast<ushort_t*>(&b);
}
__device__ __forceinline__ float bf2f(ushort_t u) {
  union { unsigned int i; float f; } v; v.i = ((unsigned int)u) << 16; return v.f;
}
__device__ __forceinline__ void gload_lds16(const void* g, void* l) {
  __builtin_amdgcn_global_load_lds(
      (const __attribute__((address_space(1))) unsigned int*)g,
      (__attribute__((address_space(3))) unsigned int*)l, 16, 0, 0);
}

// ------ prep: 4 weight transposes (z<4) + 128-entry leaf table (z==4) ------
__global__ __launch_bounds__(256) void k_prep(
    const float* __restrict__ s0, const float* __restrict__ s1,
    const float* __restrict__ s2, const float* __restrict__ s3,
    ushort_t* __restrict__ d0, ushort_t* __restrict__ d1,
    ushort_t* __restrict__ d2, ushort_t* __restrict__ d3,
    const float* __restrict__ Wiou, const float* __restrict__ biou) {
  if (blockIdx.z == 4) {                     // ---- leaf table by token value
    const int v = blockIdx.y * 48 + blockIdx.x;
    if (v >= V) return;
    for (int j = threadIdx.x; j < H; j += 256) {
      float ig = Wiou[(size_t)v * 1536 + j] + biou[j];
      float og = Wiou[(size_t)v * 1536 + 512 + j] + biou[512 + j];
      float ug = Wiou[(size_t)v * 1536 + 1024 + j] + biou[1024 + j];
      float c = sigm(ig) * ftanh(ug);
      float h = sigm(og) * ftanh(c);
      g_htab[v * H + j] = f2bf(h);
      g_ctab[v * H + j] = c;
    }
    return;
  }
  // ---- transpose+bf16: dst[c][r] = bf16(src[r][c]) ----
  const float* src; ushort_t* dst; int R, Cc;
  switch (blockIdx.z) {
    case 0: src = s0; dst = d0; R = 1024; Cc = 1536; break;
    case 1: src = s1; dst = d1; R = 1024; Cc = 512; break;
    case 2: src = s2; dst = d2; R = 1536; Cc = 1536; break;
    default: src = s3; dst = d3; R = 1536; Cc = 512; break;
  }
  int bc = blockIdx.x * 32, br = blockIdx.y * 32;
  if (bc >= Cc || br >= R) return;
  __shared__ float t[32][33];
  int tx = threadIdx.x & 31, ty = threadIdx.x >> 5;
  for (int rr = ty; rr < 32; rr += 8)
    t[rr][tx] = src[(size_t)(br + rr) * Cc + bc + tx];
  __syncthreads();
  for (int rr = ty; rr < 32; rr += 8)
    dst[(size_t)(bc + rr) * R + br + tx] = f2bf(t[tx][rr]);
}

// ====== shared MFMA compute macro (16x16x32 bf16, 4 waves 2rx2c) ======
#define MFMA_COMPUTE(FA)                                                     \
  {                                                                          \
    const char* ab = smem + buf * 8192 + wry * 4096 + lane * 16;             \
    s16x8 a0 = *(const s16x8*)(ab);                                          \
    s16x8 a1 = *(const s16x8*)(ab + 1024);                                   \
    s16x8 a2 = *(const s16x8*)(ab + 2048);                                   \
    s16x8 a3 = *(const s16x8*)(ab + 3072);                                   \
    const char* bb = smem + 24576 + buf * 16384 + cx * 2048 + lane * 16;     \
    s16x8 b0 = *(const s16x8*)(bb);                                          \
    s16x8 b1 = *(const s16x8*)(bb + 1024);                                   \
    s16x8 b2 = *(const s16x8*)(bb + 4096);                                   \
    s16x8 b3 = *(const s16x8*)(bb + 5120);                                   \
    s16x8 b4 = *(const s16x8*)(bb + 8192);                                   \
    s16x8 b5 = *(const s16x8*)(bb + 9216);                                   \
    s16x8 b6 = *(const s16x8*)(bb + 12288);                                  \
    s16x8 b7 = *(const s16x8*)(bb + 13312);                                  \
    s16x8 aa[4] = {a0, a1, a2, a3};                                          \
    _Pragma("unroll")                                                        \
    for (int rtl = 0; rtl < 4; ++rtl) {                                      \
      acc[rtl][0] = __builtin_amdgcn_mfma_f32_16x16x32_bf16(aa[rtl], b0, acc[rtl][0], 0, 0, 0); \
      acc[rtl][1] = __builtin_amdgcn_mfma_f32_16x16x32_bf16(aa[rtl], b1, acc[rtl][1], 0, 0, 0); \
      acc[rtl][2] = __builtin_amdgcn_mfma_f32_16x16x32_bf16(aa[rtl], b2, acc[rtl][2], 0, 0, 0); \
      acc[rtl][3] = __builtin_amdgcn_mfma_f32_16x16x32_bf16(aa[rtl], b3, acc[rtl][3], 0, 0, 0); \
      acc[rtl][4] = __builtin_amdgcn_mfma_f32_16x16x32_bf16(aa[rtl], b4, acc[rtl][4], 0, 0, 0); \
      acc[rtl][5] = __builtin_amdgcn_mfma_f32_16x16x32_bf16(aa[rtl], b5, acc[rtl][5], 0, 0, 0); \
      acc[rtl][FA] = __builtin_amdgcn_mfma_f32_16x16x32_bf16(aa[rtl], b6, acc[rtl][FA], 0, 0, 0); \
      acc[rtl][FA + 1] = __builtin_amdgcn_mfma_f32_16x16x32_bf16(aa[rtl], b7, acc[rtl][FA + 1], 0, 0, 0); \
    }                                                                        \
  }
#define WAITV(N) asm volatile("s_waitcnt vmcnt(" #N ")" ::: "memory")

// ----- epilogue shared across mfma kernels (c-source passed per row) -------
#define MFMA_EPILOGUE(CREAD0, CREAD1)                                        \
  {                                                                          \
    const int node_c = lane >> 4;                                            \
    const int jl = lane & 15;                                                \
    _Pragma("unroll")                                                        \
    for (int t = 0; t < 2; ++t) {                                            \
      const int j = j0 + cx * 32 + t * 16 + jl;                              \
      const float bi = biou[j], bo = biou[512 + j], bu = biou[1024 + j],     \
                  bfv = bf[j];                                               \
      _Pragma("unroll")                                                      \
      for (int rtl = 0; rtl < 4; ++rtl) {                                    \
        f32x4 vi = acc[rtl][0 + t], vo = acc[rtl][2 + t],                    \
              vu = acc[rtl][4 + t], v0 = acc[rtl][6 + t],                    \
              v1 = acc[rtl][8 + t];                                          \
        const int ib = i0 + wry * 64 + rtl * 16 + node_c * 4;                \
        _Pragma("unroll")                                                    \
        for (int r = 0; r < 4; ++r) {                                        \
          int i = ib + r;                                                    \
          int tok = tokens[node0 + i];                                       \
          const float* Wr = Wiou + (size_t)tok * 1536;                       \
          float fpre = Wf[(size_t)tok * 512 + j] + bfv;                      \
          float ig = vi[r] + Wr[j] + bi;                                     \
          float og = vo[r] + Wr[512 + j] + bo;                               \
          float ug = vu[r] + Wr[1024 + j] + bu;                              \
          float cc = sigm(ig) * ftanh(ug)                                    \
                   + sigm(fpre + v0[r]) * (CREAD0)                           \
                   + sigm(fpre + v1[r]) * (CREAD1);                          \
          float hh = sigm(og) * ftanh(cc);                                   \
          hout[(size_t)i * 512 + j] = f2bf(hh);                              \
          cout[(size_t)i * 512 + j] = cc;                                    \
        }                                                                    \
      }                                                                      \
    }                                                                        \
  }

// ---------------- lvl 13: A rows gathered from the 128-entry leaf table ----
__global__ __launch_bounds__(256, 2) void k_mfma_top(
    const int* __restrict__ tokens,
    const float* __restrict__ Wiou, const float* __restrict__ biou,
    const float* __restrict__ Wf, const float* __restrict__ bf) {
  const int node0 = 8191;                    // lvl 13
  ushort_t* __restrict__ hout = g_hb1;
  float* __restrict__ cout = g_c1;

  const int i0 = blockIdx.x * 128;
  const int j0 = blockIdx.y * 64;
  const int tid = threadIdx.x;
  const int lane = tid & 63;
  const int w = tid >> 6;
  const int wry = w >> 1;
  const int cx = w & 1;

  __shared__ f32x4 smemv[4608];  // 72KB: A 3x8KB @0, B 3x16KB @24576
  char* smem = (char*)smemv;

  // per-chunk sources: A chunks gather from g_htab via child tokens;
  // child switch (k<512 vs >=512) == staged-kt<16 vs >=16 -> p0/p1 select.
  const char* p0[6]; const char* p1[6];
  unsigned lb[6], lstr[6], mm[6];
  {
    int kb = (lane >> 4) * 16;
    #pragma unroll
    for (int q = 0; q < 6; ++q) {
      int c = w * 6 + q;
      if (c < 8) {               // A chunk, row-tile c
        int row = i0 + c * 16 + (lane & 15);
        int t0 = tokens[(NLEAF - 1) + 2 * row];
        int t1 = tokens[(NLEAF - 1) + 2 * row + 1];
        p0[q] = (const char*)g_htab + (size_t)t0 * 1024 + kb;
        p1[q] = (const char*)g_htab + (size_t)t1 * 1024 + kb;
        mm[q] = 15u;
        lb[q] = c * 1024u;
        lstr[q] = 8192u;
      } else {
        int ct = c - 8;
        int col = ct * 16 + (lane & 15);
        int g = col >> 6, jj = j0 + (col & 63);
        const ushort_t* Ub = (g < 3) ? (g_UiouT + (size_t)(g * 512 + jj) * 1024)
                                     : (g_UfT + (size_t)jj * 1024);
        p0[q] = (const char*)Ub + kb;
        p1[q] = p0[q];
        mm[q] = 63u;
        lb[q] = 24576u + ct * 1024u;
        lstr[q] = 16384u;
      }
    }
  }

#define STAGE_T(BUF, SKT)                                                    \
  {                                                                          \
    _Pragma("unroll")                                                        \
    for (int q = 0; q < 6; ++q) {                                            \
      const char* src = (((SKT) >= 16) ? p1[q] : p0[q]) +                    \
                        (((unsigned)(SKT) & mm[q]) << 6);                    \
      gload_lds16(src, smem + lb[q] + (unsigned)(BUF) * lstr[q]);            \
    }                                                                        \
  }

  f32x4 acc[4][10];
  #pragma unroll
  for (int a = 0; a < 4; ++a)
    #pragma unroll
    for (int b = 0; b < 10; ++b) acc[a][b] = (f32x4){0.f, 0.f, 0.f, 0.f};

  STAGE_T(0, 0); STAGE_T(1, 1); STAGE_T(2, 2);
  int buf = 0;
  for (int kt = 0; kt < 16; ++kt) {
    WAITV(12);
    __builtin_amdgcn_s_barrier();
    MFMA_COMPUTE(6);
    __builtin_amdgcn_s_barrier();
    STAGE_T(buf, kt + 3);
    buf = (buf == 2) ? 0 : buf + 1;
  }
  for (int kt = 16; kt < 29; ++kt) {
    WAITV(12);
    __builtin_amdgcn_s_barrier();
    MFMA_COMPUTE(8);
    __builtin_amdgcn_s_barrier();
    STAGE_T(buf, kt + 3);
    buf = (buf == 2) ? 0 : buf + 1;
  }
  WAITV(12); __builtin_amdgcn_s_barrier(); MFMA_COMPUTE(8);
  buf = (buf == 2) ? 0 : buf + 1;
  WAITV(6);  __builtin_amdgcn_s_barrier(); MFMA_COMPUTE(8);
  buf = (buf == 2) ? 0 : buf + 1;
  WAITV(0);  __builtin_amdgcn_s_barrier(); MFMA_COMPUTE(8);
#undef STAGE_T

  MFMA_EPILOGUE(g_ctab[(size_t)tokens[(NLEAF - 1) + 2 * i] * 512 + j],
                g_ctab[(size_t)tokens[(NLEAF - 1) + 2 * i + 1] * 512 + j]);
}

// ---------------- levels 12..8: round-8 structure (depth-3, 72KB) ----------
__global__ __launch_bounds__(256, 2) void k_mfma_rest(int lvl,
    const int* __restrict__ tokens,
    const float* __restrict__ Wiou, const float* __restrict__ biou,
    const float* __restrict__ Wf, const float* __restrict__ bf) {
  const int n = 1 << lvl;
  const int node0 = n - 1;
  const int outp = lvl & 1;
  const ushort_t* __restrict__ hprev = outp ? g_hb0 : g_hb1;
  const float* __restrict__ cprev = outp ? g_c0 : g_c1;
  ushort_t* __restrict__ hout = outp ? g_hb1 : g_hb0;
  float* __restrict__ cout = outp ? g_c1 : g_c0;

  const int i0 = blockIdx.x * 128;
  const int j0 = blockIdx.y * 64;
  const int tid = threadIdx.x;
  const int lane = tid & 63;
  const int w = tid >> 6;
  const int wry = w >> 1;
  const int cx = w & 1;

  __shared__ f32x4 smemv[4608];  // 72KB
  char* smem = (char*)smemv;

  const char* gp[6];
  unsigned lb[6], lstr[6];
  {
    int kb = (lane >> 4) * 16;
    #pragma unroll
    for (int q = 0; q < 6; ++q) {
      int c = w * 6 + q;
      if (c < 8) {
        int row = i0 + c * 16 + (lane & 15);
        gp[q] = (const char*)hprev + (size_t)row * 2048 + kb;
        lb[q] = c * 1024u;
        lstr[q] = 8192u;
      } else {
        int ct = c - 8;
        int col = ct * 16 + (lane & 15);
        int g = col >> 6, jj = j0 + (col & 63);
        const ushort_t* Ub = (g < 3) ? (g_UiouT + (size_t)(g * 512 + jj) * 1024)
                                     : (g_UfT + (size_t)jj * 1024);
        gp[q] = (const char*)Ub + kb;
        lb[q] = 24576u + ct * 1024u;
        lstr[q] = 16384u;
      }
    }
  }

#define STAGE_R(BUF)                                                 \
  {                                                                  \
    _Pragma("unroll")                                                \
    for (int q = 0; q < 6; ++q) {                                    \
      gload_lds16(gp[q], smem + lb[q] + (unsigned)(BUF) * lstr[q]);  \
      gp[q] += 64;                                                   \
    }                                                                \
  }

  f32x4 acc[4][10];
  #pragma unroll
  for (int a = 0; a < 4; ++a)
    #pragma unroll
    for (int b = 0; b < 10; ++b) acc[a][b] = (f32x4){0.f, 0.f, 0.f, 0.f};

  STAGE_R(0); STAGE_R(1); STAGE_R(2);
  int buf = 0;
  for (int kt = 0; kt < 16; ++kt) {
    WAITV(12);
    __builtin_amdgcn_s_barrier();
    MFMA_COMPUTE(6);
    __builtin_amdgcn_s_barrier();
    STAGE_R(buf);
    buf = (buf == 2) ? 0 : buf + 1;
  }
  for (int kt = 16; kt < 29; ++kt) {
    WAITV(12);
    __builtin_amdgcn_s_barrier();
    MFMA_COMPUTE(8);
    __builtin_amdgcn_s_barrier();
    STAGE_R(buf);
    buf = (buf == 2) ? 0 : buf + 1;
  }
  WAITV(12); __builtin_amdgcn_s_barrier(); MFMA_COMPUTE(8);
  buf = (buf == 2) ? 0 : buf + 1;
  WAITV(6);  __builtin_amdgcn_s_barrier(); MFMA_COMPUTE(8);
  buf = (buf == 2) ? 0 : buf + 1;
  WAITV(0);  __builtin_amdgcn_s_barrier(); MFMA_COMPUTE(8);
#undef STAGE_R

  MFMA_EPILOGUE(cprev[(size_t)(2 * i) * 512 + j],
                cprev[(size_t)(2 * i + 1) * 512 + j]);
}

// ------------- small levels (n <= 128): single fused GEMV kernel -----------
__global__ __launch_bounds__(256) void k_small(int lvl,
    const int* __restrict__ tokens,
    const float* __restrict__ Wiou, const float* __restrict__ biou,
    const float* __restrict__ Wf, const float* __restrict__ bf) {
  const int n = 1 << lvl;
  const int node0 = n - 1;
  const int outp = lvl & 1;
  const ushort_t* __restrict__ hprev = outp ? g_hb0 : g_hb1;
  const float* __restrict__ cprev = outp ? g_c0 : g_c1;
  ushort_t* __restrict__ hout = outp ? g_hb1 : g_hb0;
  float* __restrict__ cout = outp ? g_c1 : g_c0;

  const int i = blockIdx.y;
  const int j0 = blockIdx.x * 64;
  const int tid = threadIdx.x;
  const int g = tid >> 6;
  const int jc = tid & 63;
  const int jj = j0 + jc;

  __shared__ float hl[1024];
  __shared__ float exch[5][64];
  for (int t = tid; t < 1024; t += 256) hl[t] = bf2f(hprev[(size_t)i * 1024 + t]);
  __syncthreads();

  const ushort_t* col = (g < 3) ? (g_UiouT + (size_t)(g * 512 + jj) * 1024)
                                : (g_UfT + (size_t)jj * 1024);
  float a0 = 0.f, a1 = 0.f;
  #pragma unroll 4
  for (int k0 = 0; k0 < 512; k0 += 8) {
    s16x8 wv = *(const s16x8*)(col + k0);
    #pragma unroll
    for (int r = 0; r < 8; ++r) a0 += hl[k0 + r] * bf2f((ushort_t)wv[r]);
  }
  #pragma unroll 4
  for (int k0 = 512; k0 < 1024; k0 += 8) {
    s16x8 wv = *(const s16x8*)(col + k0);
    #pragma unroll
    for (int r = 0; r < 8; ++r) a1 += hl[k0 + r] * bf2f((ushort_t)wv[r]);
  }
  if (g < 3) exch[g][jc] = a0 + a1;
  else { exch[3][jc] = a0; exch[4][jc] = a1; }
  __syncthreads();

  if (tid < 64) {
    int j = j0 + tid;
    float ai = exch[0][tid], ao = exch[1][tid], au = exch[2][tid];
    float af0 = exch[3][tid], af1 = exch[4][tid];
    int tok = tokens[node0 + i];
    const float* Wr = Wiou + (size_t)tok * 1536;
    float fpre = Wf[(size_t)tok * 512 + j] + bf[j];
    float ig = ai + Wr[j] + biou[j];
    float og = ao + Wr[512 + j] + biou[512 + j];
    float ug = au + Wr[1024 + j] + biou[1024 + j];
    float cc = sigm(ig) * ftanh(ug)
             + sigm(fpre + af0) * cprev[(size_t)(2 * i) * 512 + j]
             + sigm(fpre + af1) * cprev[(size_t)(2 * i + 1) * 512 + j];
    float hh = sigm(og) * ftanh(cc);
    hout[(size_t)i * 512 + j] = f2bf(hh);
    cout[(size_t)i * 512 + j] = cc;
  }
}

// ---------------- root ternary cell: 2-phase k-split -----------------------
__global__ __launch_bounds__(256) void k_root_p1() {
  const int by = blockIdx.y;
  const int tid = threadIdx.x;
  const int c = blockIdx.x * 256 + tid;      // 0..3071

  __shared__ float hl[512];
  {
    int m0 = by * 512;
    #pragma unroll
    for (int q = 0; q < 2; ++q) {
      int t = tid + q * 256, m = m0 + t;
      hl[t] = (m < 512) ? bf2f(g_hb0[m]) : bf2f(g_hb1[m - 512]);
    }
  }
  __syncthreads();

  float acc = 0.f;
  const ushort_t* col = nullptr;
  if (c < 1536) {
    col = g_UiouTt + (size_t)c * 1536 + by * 512;
  } else {
    int v = c - 1536;
    if ((v >> 9) == by) col = g_UfTt + (size_t)(v & 511) * 1536 + by * 512;
  }
  if (col) {
    #pragma unroll 4
    for (int k0 = 0; k0 < 512; k0 += 8) {
      s16x8 wv = *(const s16x8*)(col + k0);
      #pragma unroll
      for (int r = 0; r < 8; ++r) acc += hl[k0 + r] * bf2f((ushort_t)wv[r]);
    }
  }
  g_rpart[(size_t)by * 3072 + c] = acc;
}

// ---------------- root phase 2 + FFN head, single block --------------------
__global__ __launch_bounds__(512) void k_p2h1(const int* __restrict__ tokens,
    const float* __restrict__ Wiou_t, const float* __restrict__ biou_t,
    const float* __restrict__ Wf_t, const float* __restrict__ bf_t,
    const float* __restrict__ ffnW, const float* __restrict__ ffnb) {
  __shared__ float hroot[H];
  const int j = threadIdx.x;
  float ai = g_rpart[j] + g_rpart[3072 + j] + g_rpart[6144 + j];
  float ao = g_rpart[512 + j] + g_rpart[3072 + 512 + j] + g_rpart[6144 + 512 + j];
  float au = g_rpart[1024 + j] + g_rpart[3072 + 1024 + j] + g_rpart[6144 + 1024 + j];
  float f0 = g_rpart[1536 + j] + g_rpart[3072 + 1536 + j] + g_rpart[6144 + 1536 + j];
  float f1 = g_rpart[2048 + j] + g_rpart[3072 + 2048 + j] + g_rpart[6144 + 2048 + j];
  float f2 = g_rpart[2560 + j] + g_rpart[3072 + 2560 + j] + g_rpart[6144 + 2560 + j];

  int tok = tokens[0];
  float fpre = Wf_t[(size_t)tok * H + j] + bf_t[j];
  float ig = ai + Wiou_t[(size_t)tok * 3 * H + j] + biou_t[j];
  float og = ao + Wiou_t[(size_t)tok * 3 * H + H + j] + biou_t[H + j];
  float ug = au + Wiou_t[(size_t)tok * 3 * H + 2 * H + j] + biou_t[2 * H + j];
  float cc = sigm(ig) * ftanh(ug)
           + sigm(fpre + f0) * g_c0[j]
           + sigm(fpre + f1) * g_c1[j]
           + sigm(fpre + f2) * g_c1[H + j];
  hroot[j] = sigm(og) * ftanh(cc);
  __syncthreads();

  float acc = ffnb[j];
  #pragma unroll 8
  for (int m = 0; m < H; ++m) acc += hroot[m] * ffnW[m * H + j];
  g_hf[j] = fmaxf(acc, 0.0f);
}

// ---------------- head2: only the 1536 live gates (gf dead: c_g=0) ---------
__global__ __launch_bounds__(64) void k_head2(const float* __restrict__ Wx,
                                              const float* __restrict__ lb) {
  int idx = blockIdx.x * 64 + threadIdx.x;   // 0..1535
  int region = idx >> 9;                      // 0 gi, 1 gg, 2 go
  int j = idx & 511;
  int g2 = (region == 0) ? j : ((region == 1) ? 1024 + j : 1536 + j);
  float acc = lb[g2];
  #pragma unroll 8
  for (int m = 0; m < H; ++m) acc += g_hf[m] * Wx[m * 4 * H + g2];
  g_gates[g2] = acc;  // h_g starts at 0 so Wh term vanishes
}

__global__ __launch_bounds__(512) void k_head3(const float* __restrict__ vm,
    const float* __restrict__ hlW, const float* __restrict__ hlb,
    const float* __restrict__ intW, const float* __restrict__ intb,
    const float* __restrict__ actW, const float* __restrict__ actb,
    float* __restrict__ out) {
  __shared__ float feat[2 * H];
  int j = threadIdx.x;
  float ci = sigm(g_gates[j]) * ftanh(g_gates[2 * H + j]);
  float hg = sigm(g_gates[3 * H + j]) * ftanh(ci);
  feat[j] = g_hf[j];
  feat[H + j] = hg;
  __syncthreads();

  const int wv = threadIdx.x >> 6;
  const int lane = threadIdx.x & 63;
  for (int o = wv; o < 43; o += 8) {
    const float* Wc;
    int stride, colb;
    if (o < 2)       { Wc = hlW;  stride = 2;  colb = o; }
    else if (o < 7)  { Wc = intW; stride = 5;  colb = o - 2; }
    else             { Wc = actW; stride = 36; colb = o - 7; }
    float s = 0.f;
    #pragma unroll
    for (int q = 0; q < 16; ++q) {
      int m = lane + q * 64;
      s += feat[m] * Wc[(size_t)m * stride + colb];
    }
    #pragma unroll
    for (int d = 32; d >= 1; d >>= 1) s += __shfl_xor(s, d);
    if (lane == 0) {
      float res;
      if (o < 2)      res = s + hlb[o];
      else if (o < 7) res = s + intb[o - 2];
      else {
        int a = o - 7;
        float v = vm[a];
        res = __logf(v) + s * v + actb[a] * v;
      }
      out[o] = res;
    }
  }
}

extern "C" void kernel_launch(void* const* d_in, const int* in_sizes, int n_in,
                              void* d_out, int out_size, void* d_ws, size_t ws_size,
                              hipStream_t stream) {
  (void)in_sizes; (void)n_in; (void)d_ws; (void)ws_size; (void)out_size;
  const int* tokens   = (const int*)d_in[0];
  const float* vm     = (const float*)d_in[1];
  const float* Wiou_b = (const float*)d_in[2];
  const float* Uiou_b = (const float*)d_in[3];
  const float* biou_b = (const float*)d_in[4];
  const float* Wf_b   = (const float*)d_in[5];
  const float* Uf_b   = (const float*)d_in[6];
  const float* bf_b   = (const float*)d_in[7];
  const float* Wiou_t = (const float*)d_in[8];
  const float* Uiou_t = (const float*)d_in[9];
  const float* biou_t = (const float*)d_in[10];
  const float* Wf_t   = (const float*)d_in[11];
  const float* Uf_t   = (const float*)d_in[12];
  const float* bf_t   = (const float*)d_in[13];
  const float* ffnW   = (const float*)d_in[14];
  const float* ffnb   = (const float*)d_in[15];
  const float* lstmWx = (const float*)d_in[16];
  const float* lstmb  = (const float*)d_in[18];
  const float* hlW    = (const float*)d_in[19];
  const float* hlb    = (const float*)d_in[20];
  const float* intW   = (const float*)d_in[21];
  const float* intb   = (const float*)d_in[22];
  const float* actW   = (const float*)d_in[23];
  const float* actb   = (const float*)d_in[24];

  ushort_t* UiouT;  hipGetSymbolAddress((void**)&UiouT, HIP_SYMBOL(g_UiouT));
  ushort_t* UfT;    hipGetSymbolAddress((void**)&UfT, HIP_SYMBOL(g_UfT));
  ushort_t* UiouTt; hipGetSymbolAddress((void**)&UiouTt, HIP_SYMBOL(g_UiouTt));
  ushort_t* UfTt;   hipGetSymbolAddress((void**)&UfTt, HIP_SYMBOL(g_UfTt));

  // transposes + leaf table in one launch
  k_prep<<<dim3(48, 48, 5), 256, 0, stream>>>(
      Uiou_b, Uf_b, Uiou_t, Uf_t, UiouT, UfT, UiouTt, UfTt, Wiou_b, biou_b);

  k_mfma_top<<<dim3(64, 8), 256, 0, stream>>>(tokens, Wiou_b, biou_b,
                                              Wf_b, bf_b);
  for (int lvl = 12; lvl >= 8; --lvl) {
    int gx = (1 << lvl) / 128;
    k_mfma_rest<<<dim3(gx, 8), 256, 0, stream>>>(lvl, tokens, Wiou_b, biou_b,
                                                 Wf_b, bf_b);
  }
  for (int lvl = 7; lvl >= 0; --lvl) {
    int n = 1 << lvl;
    k_small<<<dim3(8, n), 256, 0, stream>>>(lvl, tokens, Wiou_b, biou_b,
                                            Wf_b, bf_b);
  }
  k_root_p1<<<dim3(12, 3), 256, 0, stream>>>();
  k_p2h1<<<1, 512, 0, stream>>>(tokens, Wiou_t, biou_t, Wf_t, bf_t, ffnW, ffnb);
  k_head2<<<24, 64, 0, stream>>>(lstmWx, lstmb);
  k_head3<<<1, 512, 0, stream>>>(vm, hlW, hlb, intW, intb, actW, actb, (float*)d_out);
}